// Round 1
// baseline (10354.728 us; speedup 1.0000x reference)
//
#include <hip/hip_runtime.h>

typedef unsigned short u16;

#define NSYM 512

// ---------------------------------------------------------------------------
// Build u16 copies of the luts + fused relu(add_lut) table
// ---------------------------------------------------------------------------
__global__ void build_tables_kernel(const int* __restrict__ conv_i,
                                    const int* __restrict__ add_i,
                                    const int* __restrict__ relu_i,
                                    u16* __restrict__ conv_u,
                                    u16* __restrict__ add_u,
                                    u16* __restrict__ addrelu_u) {
    int i = blockIdx.x * blockDim.x + threadIdx.x;
    if (i < NSYM * NSYM) {
        conv_u[i] = (u16)conv_i[i];
        int a = add_i[i];
        add_u[i] = (u16)a;
        addrelu_u[i] = (u16)relu_i[a];
    }
}

// ---------------------------------------------------------------------------
// Quantize: argmin over sorted centroids == binary search + neighbor compare.
// Tie ((v-c_lo)^2 == (v-c_hi)^2) -> lower index (argmin picks first min).
// Output layout: (img, y, x, ch) ch fastest  (matches img.transpose(1,2,0))
// ---------------------------------------------------------------------------
__global__ void quantize_kernel(const float* __restrict__ x,
                                u16* __restrict__ s0,
                                const float* __restrict__ cent,
                                int n) {
    __shared__ float c[NSYM];
    for (int t = threadIdx.x; t < NSYM; t += blockDim.x) c[t] = cent[t];
    __syncthreads();
    int i = blockIdx.x * blockDim.x + threadIdx.x;
    if (i >= n) return;
    int ch = i % 3; int t2 = i / 3; int xx = t2 % 67; int t3 = t2 / 67;
    int y = t3 % 67; int img = t3 / 67;
    float v = x[((img * 3 + ch) * 67 + y) * 67 + xx];
    int lo = 0, hi = NSYM;
    while (lo < hi) { int mid = (lo + hi) >> 1; if (c[mid] < v) lo = mid + 1; else hi = mid; }
    int idx;
    if (lo == 0) idx = 0;
    else if (lo == NSYM) idx = NSYM - 1;
    else {
        float d1 = v - c[lo - 1];
        float d2 = v - c[lo];
        idx = (d1 * d1 <= d2 * d2) ? (lo - 1) : lo;
    }
    s0[i] = (u16)idx;
}

// ---------------------------------------------------------------------------
// Symbolic conv layer. One block per output pixel, OC threads (one per out ch).
// Patch (k*k*C symbols) staged in LDS; j order = (kr, kc, c) with c fastest
// (matches reference reshape). Chain: carry=m0; carry=add[carry, m_j].
// Last step uses `addlast` (fused relu table on relu layers).
// Depth-3 rotating prefetch keeps the independent conv gathers off the
// dependent add-gather critical path.
// ---------------------------------------------------------------------------
__global__ void symconv_kernel(const u16* __restrict__ in, u16* __restrict__ out,
                               const int* __restrict__ Wl,
                               const u16* __restrict__ conv,
                               const u16* __restrict__ addt,
                               const u16* __restrict__ addlast,
                               int H, int Wd, int C, int OC,
                               int K, int ST, int PAD, int OH, int OW) {
    extern __shared__ u16 patch[];
    int pix = blockIdx.x;
    int img = pix / (OH * OW);
    int rem = pix - img * (OH * OW);
    int oy = rem / OW;
    int ox = rem - oy * OW;
    int J = K * K * C;
    for (int t = threadIdx.x; t < J; t += blockDim.x) {
        int c = t % C; int tt = t / C; int kc = tt % K; int kr = tt / K;
        int iy = oy * ST + kr - PAD;
        int ix = ox * ST + kc - PAD;
        u16 v = 0;  // jnp.pad pads with symbol 0
        if (iy >= 0 && iy < H && ix >= 0 && ix < Wd)
            v = in[((img * H + iy) * Wd + ix) * C + c];
        patch[t] = v;
    }
    __syncthreads();
    int oc = threadIdx.x;

#define GM(j) ((int)conv[((int)patch[(j)] << 9) + Wl[(j) * OC + oc]])

    int carry = GM(0);
    int mA = GM(1);
    int mB = GM(2);
    int mC = GM(3);
    for (int j = 1; j < J - 3; ++j) {
        int mcur = mA; mA = mB; mB = mC;
        mC = GM(j + 3);
        carry = (int)addt[(carry << 9) + mcur];
    }
    carry = (int)addt[(carry << 9) + mA];
    carry = (int)addt[(carry << 9) + mB];
    carry = (int)addlast[(carry << 9) + mC];
    out[pix * OC + oc] = (u16)carry;
#undef GM
}

// ---------------------------------------------------------------------------
// Head: vals = centroid[s]; feats = mean over 2x2; out = feats @ fc_w.T + fc_b
// ---------------------------------------------------------------------------
__global__ void head_kernel(const u16* __restrict__ s,
                            const float* __restrict__ cent,
                            const float* __restrict__ fcw,
                            const float* __restrict__ fcb,
                            float* __restrict__ out) {
    __shared__ float feats[NSYM];
    int img = blockIdx.x;
    const u16* sp = s + img * 4 * NSYM;
    for (int c = threadIdx.x; c < NSYM; c += blockDim.x) {
        float acc = cent[sp[c]] + cent[sp[NSYM + c]] +
                    cent[sp[2 * NSYM + c]] + cent[sp[3 * NSYM + c]];
        feats[c] = acc * 0.25f;
    }
    __syncthreads();
    int o = blockIdx.y * blockDim.x + threadIdx.x;
    if (o < 1000) {
        float acc = fcb[o];
        const float* wr = fcw + o * NSYM;
        for (int c2 = 0; c2 < NSYM; ++c2) acc += feats[c2] * wr[c2];
        out[img * 1000 + o] = acc;
    }
}

// ---------------------------------------------------------------------------
extern "C" void kernel_launch(void* const* d_in, const int* in_sizes, int n_in,
                              void* d_out, int out_size, void* d_ws, size_t ws_size,
                              hipStream_t stream) {
    const float* x = (const float*)d_in[0];
    const int* w[17];
    for (int i = 0; i < 17; ++i) w[i] = (const int*)d_in[1 + i];
    const int* conv_i = (const int*)d_in[18];
    const int* add_i  = (const int*)d_in[19];
    const int* relu_i = (const int*)d_in[20];
    const float* cent = (const float*)d_in[21];
    const float* fcw  = (const float*)d_in[22];
    const float* fcb  = (const float*)d_in[23];
    float* out = (float*)d_out;

    char* p = (char*)d_ws;
    u16* conv_u    = (u16*)p; p += NSYM * NSYM * 2;
    u16* add_u     = (u16*)p; p += NSYM * NSYM * 2;
    u16* addrelu_u = (u16*)p; p += NSYM * NSYM * 2;
    u16* act0      = (u16*)p; p += ((8 * 67 * 67 * 3 * 2 + 255) / 256) * 256;
    u16* actA      = (u16*)p; p += 8 * 16 * 16 * 64 * 2;
    u16* actB      = (u16*)p; p += 8 * 16 * 16 * 64 * 2;

    build_tables_kernel<<<(NSYM * NSYM + 255) / 256, 256, 0, stream>>>(
        conv_i, add_i, relu_i, conv_u, add_u, addrelu_u);

    int nq = 8 * 67 * 67 * 3;
    quantize_kernel<<<(nq + 255) / 256, 256, 0, stream>>>(x, act0, cent, nq);

    struct LC { int K, ST, PAD, C, OC, H, OH, relu; };
    static const LC L[17] = {
        {7,4,0,  3, 64,67,16,1},
        {3,1,1, 64, 64,16,16,1},
        {3,1,1, 64, 64,16,16,0},
        {3,1,1, 64, 64,16,16,1},
        {3,1,1, 64, 64,16,16,0},
        {3,2,1, 64,128,16, 8,1},
        {3,1,1,128,128, 8, 8,0},
        {3,1,1,128,128, 8, 8,1},
        {3,1,1,128,128, 8, 8,0},
        {3,2,1,128,256, 8, 4,1},
        {3,1,1,256,256, 4, 4,0},
        {3,1,1,256,256, 4, 4,1},
        {3,1,1,256,256, 4, 4,0},
        {3,2,1,256,512, 4, 2,1},
        {3,1,1,512,512, 2, 2,0},
        {3,1,1,512,512, 2, 2,1},
        {3,1,1,512,512, 2, 2,0},
    };

    const u16* cur = act0;
    u16* nxt = actA;
    for (int i = 0; i < 17; ++i) {
        int OH = L[i].OH, OW = L[i].OH;
        int grid = 8 * OH * OW;
        int J = L[i].K * L[i].K * L[i].C;
        symconv_kernel<<<grid, L[i].OC, J * 2, stream>>>(
            cur, nxt, w[i], conv_u, add_u, L[i].relu ? addrelu_u : add_u,
            L[i].H, L[i].H, L[i].C, L[i].OC,
            L[i].K, L[i].ST, L[i].PAD, OH, OW);
        cur = nxt;
        nxt = (nxt == actA) ? actB : actA;
    }

    head_kernel<<<dim3(8, 4), 256, 0, stream>>>(cur, cent, fcw, fcb, out);
}

// Round 2
// 6376.020 us; speedup vs baseline: 1.6240x; 1.6240x over previous
//
#include <hip/hip_runtime.h>

typedef unsigned short u16;

#define NSYM 512

// ---------------------------------------------------------------------------
// Build u16 copies of the luts + fused relu(add_lut) table
// ---------------------------------------------------------------------------
__global__ void build_tables_kernel(const int* __restrict__ conv_i,
                                    const int* __restrict__ add_i,
                                    const int* __restrict__ relu_i,
                                    u16* __restrict__ conv_u,
                                    u16* __restrict__ add_u,
                                    u16* __restrict__ addrelu_u) {
    int i = blockIdx.x * blockDim.x + threadIdx.x;
    if (i < NSYM * NSYM) {
        conv_u[i] = (u16)conv_i[i];
        int a = add_i[i];
        add_u[i] = (u16)a;
        addrelu_u[i] = (u16)relu_i[a];
    }
}

// ---------------------------------------------------------------------------
// Quantize: argmin over sorted centroids == binary search + neighbor compare.
// Tie -> lower index (argmin first-min semantics).
// Output layout: (img, y, x, ch) ch fastest
// ---------------------------------------------------------------------------
__global__ void quantize_kernel(const float* __restrict__ x,
                                u16* __restrict__ s0,
                                const float* __restrict__ cent,
                                int n) {
    __shared__ float c[NSYM];
    for (int t = threadIdx.x; t < NSYM; t += blockDim.x) c[t] = cent[t];
    __syncthreads();
    int i = blockIdx.x * blockDim.x + threadIdx.x;
    if (i >= n) return;
    int ch = i % 3; int t2 = i / 3; int xx = t2 % 67; int t3 = t2 / 67;
    int y = t3 % 67; int img = t3 / 67;
    float v = x[((img * 3 + ch) * 67 + y) * 67 + xx];
    int lo = 0, hi = NSYM;
    while (lo < hi) { int mid = (lo + hi) >> 1; if (c[mid] < v) lo = mid + 1; else hi = mid; }
    int idx;
    if (lo == 0) idx = 0;
    else if (lo == NSYM) idx = NSYM - 1;
    else {
        float d1 = v - c[lo - 1];
        float d2 = v - c[lo];
        idx = (d1 * d1 <= d2 * d2) ? (lo - 1) : lo;
    }
    s0[i] = (u16)idx;
}

// ---------------------------------------------------------------------------
// Symbolic conv layer. 64-thread blocks; each block handles one output pixel
// and a 64-wide slice of out-channels (oc-group). Deep layers thus spread to
// 256 blocks = 1 wave/CU: chains are the critical path, and minimum waves/CU
// minimizes TA/L2 queueing on the dependent add_lut gather.
// Patch (k*k*C symbols) staged in LDS; j order = (kr, kc, c), c fastest.
// Depth-3 rotating prefetch keeps conv gathers off the dependent-gather
// critical path.
// ---------------------------------------------------------------------------
__global__ __launch_bounds__(64) void symconv_kernel(
                               const u16* __restrict__ in, u16* __restrict__ out,
                               const int* __restrict__ Wl,
                               const u16* __restrict__ conv,
                               const u16* __restrict__ addt,
                               const u16* __restrict__ addlast,
                               int H, int Wd, int C, int OC, int nOCG,
                               int K, int ST, int PAD, int OH, int OW) {
    extern __shared__ u16 patch[];
    int bid = blockIdx.x;
    int ocg = bid % nOCG;
    int pix = bid / nOCG;
    int img = pix / (OH * OW);
    int rem = pix - img * (OH * OW);
    int oy = rem / OW;
    int ox = rem - oy * OW;
    int J = K * K * C;
    for (int t = threadIdx.x; t < J; t += 64) {
        int c = t % C; int tt = t / C; int kc = tt % K; int kr = tt / K;
        int iy = oy * ST + kr - PAD;
        int ix = ox * ST + kc - PAD;
        u16 v = 0;  // jnp.pad pads with symbol 0
        if (iy >= 0 && iy < H && ix >= 0 && ix < Wd)
            v = in[((img * H + iy) * Wd + ix) * C + c];
        patch[t] = v;
    }
    __syncthreads();
    int oc = ocg * 64 + threadIdx.x;

#define GM(j) ((int)conv[((int)patch[(j)] << 9) + Wl[(j) * OC + oc]])

    int carry = GM(0);
    int mA = GM(1);
    int mB = GM(2);
    int mC = GM(3);
    for (int j = 1; j < J - 3; ++j) {
        int mcur = mA; mA = mB; mB = mC;
        mC = GM(j + 3);
        carry = (int)addt[(carry << 9) + mcur];
    }
    carry = (int)addt[(carry << 9) + mA];
    carry = (int)addt[(carry << 9) + mB];
    carry = (int)addlast[(carry << 9) + mC];
    out[pix * OC + oc] = (u16)carry;
#undef GM
}

// ---------------------------------------------------------------------------
// Head: vals = centroid[s]; feats = mean over 2x2; out = feats @ fc_w.T + fc_b
// ---------------------------------------------------------------------------
__global__ void head_kernel(const u16* __restrict__ s,
                            const float* __restrict__ cent,
                            const float* __restrict__ fcw,
                            const float* __restrict__ fcb,
                            float* __restrict__ out) {
    __shared__ float feats[NSYM];
    int img = blockIdx.x;
    const u16* sp = s + img * 4 * NSYM;
    for (int c = threadIdx.x; c < NSYM; c += blockDim.x) {
        float acc = cent[sp[c]] + cent[sp[NSYM + c]] +
                    cent[sp[2 * NSYM + c]] + cent[sp[3 * NSYM + c]];
        feats[c] = acc * 0.25f;
    }
    __syncthreads();
    int o = blockIdx.y * blockDim.x + threadIdx.x;
    if (o < 1000) {
        float acc = fcb[o];
        const float* wr = fcw + o * NSYM;
        for (int c2 = 0; c2 < NSYM; ++c2) acc += feats[c2] * wr[c2];
        out[img * 1000 + o] = acc;
    }
}

// ---------------------------------------------------------------------------
extern "C" void kernel_launch(void* const* d_in, const int* in_sizes, int n_in,
                              void* d_out, int out_size, void* d_ws, size_t ws_size,
                              hipStream_t stream) {
    const float* x = (const float*)d_in[0];
    const int* w[17];
    for (int i = 0; i < 17; ++i) w[i] = (const int*)d_in[1 + i];
    const int* conv_i = (const int*)d_in[18];
    const int* add_i  = (const int*)d_in[19];
    const int* relu_i = (const int*)d_in[20];
    const float* cent = (const float*)d_in[21];
    const float* fcw  = (const float*)d_in[22];
    const float* fcb  = (const float*)d_in[23];
    float* out = (float*)d_out;

    char* p = (char*)d_ws;
    u16* conv_u    = (u16*)p; p += NSYM * NSYM * 2;
    u16* add_u     = (u16*)p; p += NSYM * NSYM * 2;
    u16* addrelu_u = (u16*)p; p += NSYM * NSYM * 2;
    u16* act0      = (u16*)p; p += ((8 * 67 * 67 * 3 * 2 + 255) / 256) * 256;
    u16* actA      = (u16*)p; p += 8 * 16 * 16 * 64 * 2;
    u16* actB      = (u16*)p; p += 8 * 16 * 16 * 64 * 2;

    build_tables_kernel<<<(NSYM * NSYM + 255) / 256, 256, 0, stream>>>(
        conv_i, add_i, relu_i, conv_u, add_u, addrelu_u);

    int nq = 8 * 67 * 67 * 3;
    quantize_kernel<<<(nq + 255) / 256, 256, 0, stream>>>(x, act0, cent, nq);

    struct LC { int K, ST, PAD, C, OC, H, OH, relu; };
    static const LC L[17] = {
        {7,4,0,  3, 64,67,16,1},
        {3,1,1, 64, 64,16,16,1},
        {3,1,1, 64, 64,16,16,0},
        {3,1,1, 64, 64,16,16,1},
        {3,1,1, 64, 64,16,16,0},
        {3,2,1, 64,128,16, 8,1},
        {3,1,1,128,128, 8, 8,0},
        {3,1,1,128,128, 8, 8,1},
        {3,1,1,128,128, 8, 8,0},
        {3,2,1,128,256, 8, 4,1},
        {3,1,1,256,256, 4, 4,0},
        {3,1,1,256,256, 4, 4,1},
        {3,1,1,256,256, 4, 4,0},
        {3,2,1,256,512, 4, 2,1},
        {3,1,1,512,512, 2, 2,0},
        {3,1,1,512,512, 2, 2,1},
        {3,1,1,512,512, 2, 2,0},
    };

    const u16* cur = act0;
    u16* nxt = actA;
    for (int i = 0; i < 17; ++i) {
        int OH = L[i].OH, OW = L[i].OH;
        int nOCG = L[i].OC / 64;
        int grid = 8 * OH * OW * nOCG;
        int J = L[i].K * L[i].K * L[i].C;
        symconv_kernel<<<grid, 64, J * 2, stream>>>(
            cur, nxt, w[i], conv_u, add_u, L[i].relu ? addrelu_u : add_u,
            L[i].H, L[i].H, L[i].C, L[i].OC, nOCG,
            L[i].K, L[i].ST, L[i].PAD, OH, OW);
        cur = nxt;
        nxt = (nxt == actA) ? actB : actA;
    }

    head_kernel<<<dim3(8, 4), 256, 0, stream>>>(cur, cent, fcw, fcb, out);
}